// Round 4
// baseline (54943.622 us; speedup 1.0000x reference)
//
#include <hip/hip_runtime.h>
#include <math.h>

// Problem constants: N=64, S=512, D=512, C=1024
#define DD 512
#define SS 512
#define NB 64
#define CC 1024
#define FF 2048
#define LN_EPS 1e-5f

__device__ __forceinline__ float sigf(float x) {
  return 1.0f / (1.0f + __expf(-x));
}
__device__ __forceinline__ float geluf(float x) {
  float u = 1.5957691216057308f * (x + 0.044715f * x * x * x);
  return x / (1.0f + __expf(-u));
}

// ---- fast grid barrier: per-block epoch flags, agent-scope fences --------
__device__ __forceinline__ void gbar(unsigned* __restrict__ flags,
                                     unsigned ep) {
  __builtin_amdgcn_fence(__ATOMIC_RELEASE, "agent");  // flush my L2 writes
  __syncthreads();  // all waves' stores drained (vmcnt) + fenced
  if (threadIdx.x == 0) {
    __hip_atomic_store(&flags[blockIdx.x], ep, __ATOMIC_RELAXED,
                       __HIP_MEMORY_SCOPE_AGENT);
  }
  if (threadIdx.x < 256) {
    while (__hip_atomic_load(&flags[threadIdx.x], __ATOMIC_RELAXED,
                             __HIP_MEMORY_SCOPE_AGENT) < ep) {
      __builtin_amdgcn_s_sleep(2);
    }
  }
  __syncthreads();
  __builtin_amdgcn_fence(__ATOMIC_ACQUIRE, "agent");  // invalidate stale
}

// ---------------- prologue: seq2 = LN((seq*mask)@W_init+b_init)*mask ------
__global__ __launch_bounds__(256) void k_gemm_init(
    const float* __restrict__ A, const float* __restrict__ mask,
    const float* __restrict__ W, const float* __restrict__ bias,
    float* __restrict__ out) {
  __shared__ float As[16][65];
  __shared__ float Bs[16][65];
  const int tid = threadIdx.x;
  const int bm = blockIdx.y * 64;
  const int bn = blockIdx.x * 64;
  const int tx = tid & 15;
  const int ty = tid >> 4;
  const int idx = tid * 4;
  const int am = idx >> 4;
  const int ak = idx & 15;
  const int bk = idx >> 6;
  const int bn2 = idx & 63;
  const float mrow = mask[bm + am];
  float acc[4][4] = {};
  for (int k0 = 0; k0 < DD; k0 += 16) {
    float4 av = *(const float4*)(A + (size_t)(bm + am) * DD + k0 + ak);
    As[ak + 0][am] = av.x * mrow;
    As[ak + 1][am] = av.y * mrow;
    As[ak + 2][am] = av.z * mrow;
    As[ak + 3][am] = av.w * mrow;
    float4 bv = *(const float4*)(W + (size_t)(k0 + bk) * DD + bn + bn2);
    Bs[bk][bn2 + 0] = bv.x;
    Bs[bk][bn2 + 1] = bv.y;
    Bs[bk][bn2 + 2] = bv.z;
    Bs[bk][bn2 + 3] = bv.w;
    __syncthreads();
#pragma unroll
    for (int kk = 0; kk < 16; ++kk) {
      float a0 = As[kk][ty * 4 + 0], a1 = As[kk][ty * 4 + 1];
      float a2 = As[kk][ty * 4 + 2], a3 = As[kk][ty * 4 + 3];
      float b0 = Bs[kk][tx * 4 + 0], b1v = Bs[kk][tx * 4 + 1];
      float b2v = Bs[kk][tx * 4 + 2], b3 = Bs[kk][tx * 4 + 3];
      acc[0][0] = fmaf(a0, b0, acc[0][0]);
      acc[0][1] = fmaf(a0, b1v, acc[0][1]);
      acc[0][2] = fmaf(a0, b2v, acc[0][2]);
      acc[0][3] = fmaf(a0, b3, acc[0][3]);
      acc[1][0] = fmaf(a1, b0, acc[1][0]);
      acc[1][1] = fmaf(a1, b1v, acc[1][1]);
      acc[1][2] = fmaf(a1, b2v, acc[1][2]);
      acc[1][3] = fmaf(a1, b3, acc[1][3]);
      acc[2][0] = fmaf(a2, b0, acc[2][0]);
      acc[2][1] = fmaf(a2, b1v, acc[2][1]);
      acc[2][2] = fmaf(a2, b2v, acc[2][2]);
      acc[2][3] = fmaf(a2, b3, acc[2][3]);
      acc[3][0] = fmaf(a3, b0, acc[3][0]);
      acc[3][1] = fmaf(a3, b1v, acc[3][1]);
      acc[3][2] = fmaf(a3, b2v, acc[3][2]);
      acc[3][3] = fmaf(a3, b3, acc[3][3]);
    }
    __syncthreads();
  }
#pragma unroll
  for (int i2 = 0; i2 < 4; ++i2) {
    int row = bm + ty * 4 + i2;
#pragma unroll
    for (int j = 0; j < 4; ++j) {
      int col = bn + tx * 4 + j;
      out[(size_t)row * DD + col] = acc[i2][j] + bias[col];
    }
  }
}

__global__ __launch_bounds__(256) void k_ln_rows(
    float* __restrict__ io, const float* __restrict__ mask,
    const float* __restrict__ g, const float* __restrict__ b) {
  const int r = blockIdx.x;
  float* row = io + (size_t)r * DD;
  const int tid = threadIdx.x;
  float x0 = row[tid], x1 = row[tid + 256];
  float s = x0 + x1, ss = x0 * x0 + x1 * x1;
#pragma unroll
  for (int off = 32; off > 0; off >>= 1) {
    s += __shfl_down(s, off, 64);
    ss += __shfl_down(ss, off, 64);
  }
  __shared__ float red[8];
  int lane = tid & 63, wv = tid >> 6;
  if (lane == 0) { red[wv] = s; red[4 + wv] = ss; }
  __syncthreads();
  s = red[0] + red[1] + red[2] + red[3];
  ss = red[4] + red[5] + red[6] + red[7];
  float mean = s * (1.0f / DD);
  float var = ss * (1.0f / DD) - mean * mean;
  float rs = rsqrtf(var + LN_EPS);
  float m = mask[r];
  row[tid] = ((x0 - mean) * rs * g[tid] + b[tid]) * m;
  row[tid + 256] = ((x1 - mean) * rs * g[tid + 256] + b[tid + 256]) * m;
}

// ---- transpose seq2 (n,t,k) -> xT[t][k][n] -------------------------------
__global__ __launch_bounds__(256) void k_xt(const float* __restrict__ seq2,
                                            float* __restrict__ xT) {
  __shared__ float tl[64][65];
  const int t = blockIdx.x;
  const int kt = blockIdx.y * 64;
  const int n = threadIdx.x >> 2;
  const int f = threadIdx.x & 3;
#pragma unroll
  for (int u = 0; u < 4; ++u) {
    int k = f * 16 + u * 4;
    float4 v = *(const float4*)(seq2 + ((size_t)n * SS + t) * DD + kt + k);
    tl[k + 0][n] = v.x;
    tl[k + 1][n] = v.y;
    tl[k + 2][n] = v.z;
    tl[k + 3][n] = v.w;
  }
  __syncthreads();
  const int k2 = threadIdx.x >> 2;
#pragma unroll
  for (int u = 0; u < 4; ++u) {
    int nn = f * 16 + u * 4;
    float4 v = make_float4(tl[k2][nn], tl[k2][nn + 1], tl[k2][nn + 2],
                           tl[k2][nn + 3]);
    *(float4*)(xT + ((size_t)t * DD + kt + k2) * 64 + nn) = v;
  }
}

// ---- pack W1 per block: W1p[b][k][c] = (k<512? g[k]:1) * W1[k][4b+c] ----
__global__ __launch_bounds__(256) void k_pack1(const float* __restrict__ W1,
                                               const float* __restrict__ ln_g,
                                               float* __restrict__ W1p) {
  int i = blockIdx.x * 256 + threadIdx.x;
  int bb = i >> 12;
  int k = (i >> 2) & 1023;
  int c = i & 3;
  float v = W1[(size_t)k * CC + bb * 4 + c];
  if (k < 512) v *= ln_g[k];
  W1p[i] = v;
}

// ---- pack W2 per block: W2p[g][k][q*2+j] = W2[k][q*512+2g+j] -------------
__global__ __launch_bounds__(256) void k_pack2(const float* __restrict__ W2,
                                               float* __restrict__ W2p) {
  int i = blockIdx.x * 256 + threadIdx.x;
  int g = i >> 13;
  int k = (i >> 3) & 1023;
  int q = (i >> 1) & 3;
  int j = i & 1;
  W2p[i] = W2[(size_t)k * FF + q * 512 + 2 * g + j];
}

// ---- column sums + zero barrier flags ------------------------------------
__global__ __launch_bounds__(128) void k_cols(
    const float* __restrict__ W1, const float* __restrict__ b1,
    const float* __restrict__ ln_g, const float* __restrict__ ln_b,
    const float* __restrict__ START, float* __restrict__ Qc,
    float* __restrict__ Blnc, float* __restrict__ H0c,
    unsigned* __restrict__ flags) {
  int c = blockIdx.x * 128 + threadIdx.x;
  flags[c] = 0u;  // 8*128 = 1024 slots zeroed (only 256 used)
  float q = 0.f, bl = 0.f, h = 0.f;
  for (int k = 0; k < 512; ++k) {
    float wv = W1[(size_t)k * CC + c];
    q = fmaf(ln_g[k], wv, q);
    bl = fmaf(ln_b[k], wv, bl);
    h = fmaf(START[k], wv, h);
  }
  float bias = b1[c];
  Qc[c] = q;
  Blnc[c] = bl + bias;
  H0c[c] = h + bias;
}

// ---------------- persistent scan ----------------------------------------
__global__ __launch_bounds__(512, 1) void scan_kernel(
    float* __restrict__ outseq, float* __restrict__ gsout,
    const float* __restrict__ mask, const float* __restrict__ START,
    const float* __restrict__ W1p, const float* __restrict__ W2p,
    const float* __restrict__ b2, const float* __restrict__ ln_g,
    const float* __restrict__ ln_b, const float* __restrict__ Qc,
    const float* __restrict__ Blnc, const float* __restrict__ H0c,
    float* __restrict__ interT, float* __restrict__ zT,
    float* __restrict__ st_sum, float* __restrict__ st_ss,
    const float* __restrict__ xT, unsigned* __restrict__ flags,
    const int use_xt) {
  const int b = blockIdx.x;
  const int tid = threadIdx.x;
  const int w = tid >> 6;
  const int lane = tid & 63;
  const int d0 = 2 * b;
  unsigned ep = 0;

  __shared__ float4 pA4[8][64];
  __shared__ float4 pB4[8][64][2];

  float ht0 = 0, ht1 = 0, gs0 = 0, gs1 = 0, z0 = 0, z1 = 0;
  float gg0 = 0, gg1 = 0, bb0 = 0, bb1 = 0, mn = 0, rv = 0;
  if (tid < 64) {
    ht0 = START[d0];
    ht1 = START[d0 + 1];
    gs0 = ht0;
    gs1 = ht1;
    gg0 = ln_g[d0];
    gg1 = ln_g[d0 + 1];
    bb0 = ln_b[d0];
    bb1 = ln_b[d0 + 1];
  }
  const float4 Q4 = *(const float4*)(Qc + 4 * b);
  const float4 Bl4 = *(const float4*)(Blnc + 4 * b);
  const float4 H04 = *(const float4*)(H0c + 4 * b);
  float bb2[8];
#pragma unroll
  for (int q = 0; q < 4; ++q) {
    bb2[2 * q] = b2[q * 512 + d0];
    bb2[2 * q + 1] = b2[q * 512 + d0 + 1];
  }

  for (int t = 0; t < SS; ++t) {
    // ---------- A-head: finalize step t-1 (owners) ----------
    if (t > 0 && tid < 64) {
      const int par = ((t - 1) & 1) << 11;
      const float* sp = st_sum + par + (tid << 5);
      const float* qp = st_ss + par + (tid << 5);
      float s = 0.f, ss = 0.f;
#pragma unroll
      for (int i = 0; i < 32; i += 4) {
        float4 a4 = *(const float4*)(sp + i);
        float4 c4 = *(const float4*)(qp + i);
        s += a4.x + a4.y + a4.z + a4.w;
        ss += c4.x + c4.y + c4.z + c4.w;
      }
      float mean = s * (1.0f / DD);
      float var = ss * (1.0f / DD) - mean * mean;
      float rsv = rsqrtf(var + LN_EPS);
      mn = mean;
      rv = rsv;
      float hn0 = (z0 - mean) * rsv * gg0 + bb0;
      float hn1 = (z1 - mean) * rsv * gg1 + bb1;
      float m = mask[tid * SS + (t - 1)];
      *(float2*)(outseq + (size_t)tid * SS * DD + (size_t)(t - 1) * DD + d0) =
          make_float2(hn0 * m, hn1 * m);
      gs0 = m * hn0 + (1.0f - m) * gs0;
      gs1 = m * hn1 + (1.0f - m) * gs1;
      ht0 = hn0;
      ht1 = hn1;
    }
    if (b == 0) {  // zero parity t&1 (used by B(t) atomics after barrier 1)
      const int parz = (t & 1) << 11;
      for (int i = tid; i < 2048; i += 512) {
        st_sum[parz + i] = 0.f;
        st_ss[parz + i] = 0.f;
      }
    }
    // ---------- A waves: gemm1 partials (16-deep prefetch) ----------
    {
      const int k0 = w << 7;
      float4 acc = make_float4(0.f, 0.f, 0.f, 0.f);
      const float* wp = W1p + ((size_t)b << 12) + (k0 << 2);
      const float* ap;
      bool active = true;
      if (w < 4) {
        ap = zT + k0 * 64 + lane;
        if (t == 0) active = false;
      } else {
        const int kx = k0 - 512;
        if (use_xt) {
          ap = xT + ((size_t)t * DD + kx) * 64 + lane;
        } else {
          ap = nullptr;
        }
      }
      if (active && ap) {
        for (int c0 = 0; c0 < 128; c0 += 16) {
          float v[16];
#pragma unroll
          for (int j = 0; j < 16; ++j) v[j] = ap[(c0 + j) << 6];
#pragma unroll
          for (int j = 0; j < 16; ++j) {
            const float* wr = wp + ((c0 + j) << 2);
            acc.x = fmaf(v[j], wr[0], acc.x);
            acc.y = fmaf(v[j], wr[1], acc.y);
            acc.z = fmaf(v[j], wr[2], acc.z);
            acc.w = fmaf(v[j], wr[3], acc.w);
          }
        }
      } else if (active) {  // fallback: gather from seq2 layout
        const int kx = k0 - 512;
        const float* op =
            outseq + (size_t)lane * SS * DD + (size_t)t * DD + kx;
        for (int c0 = 0; c0 < 128; c0 += 16) {
          float4 xv[4];
#pragma unroll
          for (int j = 0; j < 4; ++j)
            xv[j] = *(const float4*)(op + c0 + 4 * j);
#pragma unroll
          for (int j = 0; j < 16; ++j) {
            const float* wr = wp + ((c0 + j) << 2);
            float x = ((const float*)xv)[j];
            acc.x = fmaf(x, wr[0], acc.x);
            acc.y = fmaf(x, wr[1], acc.y);
            acc.z = fmaf(x, wr[2], acc.z);
            acc.w = fmaf(x, wr[3], acc.w);
          }
        }
      }
      pA4[w][lane] = acc;
    }
    __syncthreads();
    // ---------- A-tail: epilogue (LN fold) + gelu -> interT ----------
    if (tid < 64) {
      float4 P = pA4[0][tid];
      float4 X = pA4[4][tid];
#pragma unroll
      for (int ww = 1; ww < 4; ++ww) {
        float4 p = pA4[ww][tid];
        P.x += p.x; P.y += p.y; P.z += p.z; P.w += p.w;
        float4 x4 = pA4[ww + 4][tid];
        X.x += x4.x; X.y += x4.y; X.z += x4.z; X.w += x4.w;
      }
      float4 o;
      if (t > 0) {
        float c1 = -rv * mn;
        o.x = fmaf(rv, P.x, fmaf(c1, Q4.x, Bl4.x)) + X.x;
        o.y = fmaf(rv, P.y, fmaf(c1, Q4.y, Bl4.y)) + X.y;
        o.z = fmaf(rv, P.z, fmaf(c1, Q4.z, Bl4.z)) + X.z;
        o.w = fmaf(rv, P.w, fmaf(c1, Q4.w, Bl4.w)) + X.w;
      } else {
        o.x = H04.x + X.x;
        o.y = H04.y + X.y;
        o.z = H04.z + X.z;
        o.w = H04.w + X.w;
      }
      interT[(4 * b + 0) * 64 + tid] = geluf(o.x);
      interT[(4 * b + 1) * 64 + tid] = geluf(o.y);
      interT[(4 * b + 2) * 64 + tid] = geluf(o.z);
      interT[(4 * b + 3) * 64 + tid] = geluf(o.w);
    }
    gbar(flags, ++ep);  // barrier 1: interT visible
    // ---------- B waves: gemm2 partials (16-deep prefetch) ----------
    {
      const int k0 = w << 7;
      float4 accL = make_float4(0.f, 0.f, 0.f, 0.f);
      float4 accH = make_float4(0.f, 0.f, 0.f, 0.f);
      const float* w2 = W2p + ((size_t)b << 13) + (k0 << 3);
      const float* ip = interT + k0 * 64 + lane;
      for (int c0 = 0; c0 < 128; c0 += 16) {
        float v[16];
#pragma unroll
        for (int j = 0; j < 16; ++j) v[j] = ip[(c0 + j) << 6];
#pragma unroll
        for (int j = 0; j < 16; ++j) {
          const float* wr = w2 + ((c0 + j) << 3);
          accL.x = fmaf(v[j], wr[0], accL.x);
          accL.y = fmaf(v[j], wr[1], accL.y);
          accL.z = fmaf(v[j], wr[2], accL.z);
          accL.w = fmaf(v[j], wr[3], accL.w);
          accH.x = fmaf(v[j], wr[4], accH.x);
          accH.y = fmaf(v[j], wr[5], accH.y);
          accH.z = fmaf(v[j], wr[6], accH.z);
          accH.w = fmaf(v[j], wr[7], accH.w);
        }
      }
      pB4[w][lane][0] = accL;
      pB4[w][lane][1] = accH;
    }
    __syncthreads();
    // ---------- B-tail: gates -> z, stats atomics (owners) ----------
    if (tid < 64) {
      float4 lo = pB4[0][tid][0];
      float4 hi = pB4[0][tid][1];
#pragma unroll
      for (int ww = 1; ww < 8; ++ww) {
        float4 p = pB4[ww][tid][0];
        lo.x += p.x; lo.y += p.y; lo.z += p.z; lo.w += p.w;
        float4 q = pB4[ww][tid][1];
        hi.x += q.x; hi.y += q.y; hi.z += q.z; hi.w += q.w;
      }
      lo.x += bb2[0]; lo.y += bb2[1]; lo.z += bb2[2]; lo.w += bb2[3];
      hi.x += bb2[4]; hi.y += bb2[5]; hi.z += bb2[6]; hi.w += bb2[7];
      float x0, x1;
      if (use_xt) {
        x0 = xT[((size_t)t * DD + d0) * 64 + tid];
        x1 = xT[((size_t)t * DD + d0 + 1) * 64 + tid];
      } else {
        float2 x2 = *(const float2*)(outseq + (size_t)tid * SS * DD +
                                     (size_t)t * DD + d0);
        x0 = x2.x;
        x1 = x2.y;
      }
      z0 = sigf(lo.x) * ht0 + sigf(lo.z) * x0 + sigf(hi.x) * hi.z;
      z1 = sigf(lo.y) * ht1 + sigf(lo.w) * x1 + sigf(hi.y) * hi.w;
      zT[d0 * 64 + tid] = z0;
      zT[(d0 + 1) * 64 + tid] = z1;
      const int par = (t & 1) << 11;
      const int slot = b & 31;
      atomicAdd(st_sum + par + (tid << 5) + slot, z0 + z1);
      atomicAdd(st_ss + par + (tid << 5) + slot, z0 * z0 + z1 * z1);
    }
    gbar(flags, ++ep);  // barrier 2: z + stats visible
  }
  // ---------- flush step 511 ----------
  if (tid < 64) {
    const int par = ((SS - 1) & 1) << 11;
    const float* sp = st_sum + par + (tid << 5);
    const float* qp = st_ss + par + (tid << 5);
    float s = 0.f, ss = 0.f;
#pragma unroll
    for (int i = 0; i < 32; i += 4) {
      float4 a4 = *(const float4*)(sp + i);
      float4 c4 = *(const float4*)(qp + i);
      s += a4.x + a4.y + a4.z + a4.w;
      ss += c4.x + c4.y + c4.z + c4.w;
    }
    float mean = s * (1.0f / DD);
    float var = ss * (1.0f / DD) - mean * mean;
    float rsv = rsqrtf(var + LN_EPS);
    float hn0 = (z0 - mean) * rsv * gg0 + bb0;
    float hn1 = (z1 - mean) * rsv * gg1 + bb1;
    float m = mask[tid * SS + (SS - 1)];
    *(float2*)(outseq + (size_t)tid * SS * DD + (size_t)(SS - 1) * DD + d0) =
        make_float2(hn0 * m, hn1 * m);
    gs0 = m * hn0 + (1.0f - m) * gs0;
    gs1 = m * hn1 + (1.0f - m) * gs1;
    *(float2*)(gsout + tid * DD + d0) = make_float2(gs0, gs1);
  }
}

// ---------------- host ----------------------------------------------------
extern "C" void kernel_launch(void* const* d_in, const int* in_sizes, int n_in,
                              void* d_out, int out_size, void* d_ws,
                              size_t ws_size, hipStream_t stream) {
  const float* seq = (const float*)d_in[0];
  const float* mask = (const float*)d_in[1];
  const float* START = (const float*)d_in[2];
  const float* W_init = (const float*)d_in[3];
  const float* b_init = (const float*)d_in[4];
  const float* W1 = (const float*)d_in[5];
  const float* b1 = (const float*)d_in[6];
  const float* W2 = (const float*)d_in[7];
  const float* b2 = (const float*)d_in[8];
  const float* ln_g = (const float*)d_in[9];
  const float* ln_b = (const float*)d_in[10];

  float* out = (float*)d_out;
  float* outseq = out;
  float* gsout = out + (size_t)NB * SS * DD;

  float* W1p = (float*)d_ws;              // 1,048,576
  float* W2p = W1p + 1048576;             // 2,097,152
  float* interT = W2p + 2097152;          // 65,536
  float* zT = interT + 65536;             // 32,768
  float* st_sum = zT + 32768;             // 4,096
  float* st_ss = st_sum + 4096;           // 4,096
  float* Qc = st_ss + 4096;               // 1,024
  float* Blnc = Qc + 1024;                // 1,024
  float* H0c = Blnc + 1024;               // 1,024
  unsigned* flags = (unsigned*)(H0c + 1024);  // 1,024 u32
  float* xT = (float*)(flags + 1024);     // 16,777,216 (optional)
  const size_t base_floats = 1048576 + 2097152 + 65536 + 32768 + 4096 + 4096 +
                             1024 + 1024 + 1024 + 1024;
  const int use_xt =
      (ws_size >= (base_floats + (size_t)16777216) * 4) ? 1 : 0;

  dim3 ga(DD / 64, (NB * SS) / 64);
  k_gemm_init<<<ga, 256, 0, stream>>>(seq, mask, W_init, b_init, outseq);
  k_ln_rows<<<NB * SS, 256, 0, stream>>>(outseq, mask, ln_g, ln_b);
  if (use_xt) {
    k_xt<<<dim3(SS, 8), 256, 0, stream>>>(outseq, xT);
  }
  k_pack1<<<4096, 256, 0, stream>>>(W1, ln_g, W1p);
  k_pack2<<<8192, 256, 0, stream>>>(W2, W2p);
  k_cols<<<8, 128, 0, stream>>>(W1, b1, ln_g, ln_b, START, Qc, Blnc, H0c,
                                flags);

  static int use_xt_copy;
  use_xt_copy = use_xt;
  void* args[] = {&outseq, &gsout,  &mask, &START, &W1p,   &W2p,
                  &b2,     &ln_g,   &ln_b, &Qc,    &Blnc,  &H0c,
                  &interT, &zT,     &st_sum, &st_ss, &xT,  &flags,
                  &use_xt_copy};
  hipLaunchCooperativeKernel((void*)scan_kernel, dim3(256), dim3(512), args, 0,
                             stream);
}

// Round 5
// 23130.414 us; speedup vs baseline: 2.3754x; 2.3754x over previous
//
#include <hip/hip_runtime.h>
#include <math.h>

// Problem constants: N=64, S=512, D=512, C=1024
#define DD 512
#define SS 512
#define NB 64
#define CC 1024
#define FF 2048
#define LN_EPS 1e-5f

__device__ __forceinline__ float sigf(float x) {
  return 1.0f / (1.0f + __expf(-x));
}
__device__ __forceinline__ float geluf(float x) {
  float u = 1.5957691216057308f * (x + 0.044715f * x * x * x);
  return x / (1.0f + __expf(-u));
}

// ---- coherent (MALL-level) scalar access: bypasses stale per-XCD L2,
// ---- NO cache-maintenance fences anywhere. --------------------------------
__device__ __forceinline__ float cload(const float* p) {
  return __hip_atomic_load(p, __ATOMIC_RELAXED, __HIP_MEMORY_SCOPE_AGENT);
}
__device__ __forceinline__ void cstore(float* p, float v) {
  __hip_atomic_store(p, v, __ATOMIC_RELAXED, __HIP_MEMORY_SCOPE_AGENT);
}

// ---- fence-free grid barrier: counter + epoch at MALL ---------------------
// sync[0],sync[1] = parity counters, sync[2] = epoch. All pre-zeroed.
__device__ __forceinline__ void gbar(unsigned* __restrict__ sync,
                                     unsigned ep) {
  // drain this wave's outstanding (coherent) stores; no cache ops
  asm volatile("s_waitcnt vmcnt(0) lgkmcnt(0)" ::: "memory");
  __syncthreads();  // all waves of this block drained + done
  if (threadIdx.x == 0) {
    unsigned old = __hip_atomic_fetch_add(&sync[ep & 1], 1u, __ATOMIC_RELAXED,
                                          __HIP_MEMORY_SCOPE_AGENT);
    if (old == 255u) {
      __hip_atomic_store(&sync[ep & 1], 0u, __ATOMIC_RELAXED,
                         __HIP_MEMORY_SCOPE_AGENT);
      asm volatile("s_waitcnt vmcnt(0)" ::: "memory");  // reset before epoch
      __hip_atomic_store(&sync[2], ep, __ATOMIC_RELAXED,
                         __HIP_MEMORY_SCOPE_AGENT);
    } else {
      unsigned v;
      do {
        __builtin_amdgcn_s_sleep(1);
        v = __hip_atomic_load(&sync[2], __ATOMIC_RELAXED,
                              __HIP_MEMORY_SCOPE_AGENT);
      } while (v < ep);
    }
  }
  __syncthreads();
}

// ---------------- prologue: seq2 = LN((seq*mask)@W_init+b_init)*mask ------
__global__ __launch_bounds__(256) void k_gemm_init(
    const float* __restrict__ A, const float* __restrict__ mask,
    const float* __restrict__ W, const float* __restrict__ bias,
    float* __restrict__ out) {
  __shared__ float As[16][65];
  __shared__ float Bs[16][65];
  const int tid = threadIdx.x;
  const int bm = blockIdx.y * 64;
  const int bn = blockIdx.x * 64;
  const int tx = tid & 15;
  const int ty = tid >> 4;
  const int idx = tid * 4;
  const int am = idx >> 4;
  const int ak = idx & 15;
  const int bk = idx >> 6;
  const int bn2 = idx & 63;
  const float mrow = mask[bm + am];
  float acc[4][4] = {};
  for (int k0 = 0; k0 < DD; k0 += 16) {
    float4 av = *(const float4*)(A + (size_t)(bm + am) * DD + k0 + ak);
    As[ak + 0][am] = av.x * mrow;
    As[ak + 1][am] = av.y * mrow;
    As[ak + 2][am] = av.z * mrow;
    As[ak + 3][am] = av.w * mrow;
    float4 bv = *(const float4*)(W + (size_t)(k0 + bk) * DD + bn + bn2);
    Bs[bk][bn2 + 0] = bv.x;
    Bs[bk][bn2 + 1] = bv.y;
    Bs[bk][bn2 + 2] = bv.z;
    Bs[bk][bn2 + 3] = bv.w;
    __syncthreads();
#pragma unroll
    for (int kk = 0; kk < 16; ++kk) {
      float a0 = As[kk][ty * 4 + 0], a1 = As[kk][ty * 4 + 1];
      float a2 = As[kk][ty * 4 + 2], a3 = As[kk][ty * 4 + 3];
      float b0 = Bs[kk][tx * 4 + 0], b1v = Bs[kk][tx * 4 + 1];
      float b2v = Bs[kk][tx * 4 + 2], b3 = Bs[kk][tx * 4 + 3];
      acc[0][0] = fmaf(a0, b0, acc[0][0]);
      acc[0][1] = fmaf(a0, b1v, acc[0][1]);
      acc[0][2] = fmaf(a0, b2v, acc[0][2]);
      acc[0][3] = fmaf(a0, b3, acc[0][3]);
      acc[1][0] = fmaf(a1, b0, acc[1][0]);
      acc[1][1] = fmaf(a1, b1v, acc[1][1]);
      acc[1][2] = fmaf(a1, b2v, acc[1][2]);
      acc[1][3] = fmaf(a1, b3, acc[1][3]);
      acc[2][0] = fmaf(a2, b0, acc[2][0]);
      acc[2][1] = fmaf(a2, b1v, acc[2][1]);
      acc[2][2] = fmaf(a2, b2v, acc[2][2]);
      acc[2][3] = fmaf(a2, b3, acc[2][3]);
      acc[3][0] = fmaf(a3, b0, acc[3][0]);
      acc[3][1] = fmaf(a3, b1v, acc[3][1]);
      acc[3][2] = fmaf(a3, b2v, acc[3][2]);
      acc[3][3] = fmaf(a3, b3, acc[3][3]);
    }
    __syncthreads();
  }
#pragma unroll
  for (int i2 = 0; i2 < 4; ++i2) {
    int row = bm + ty * 4 + i2;
#pragma unroll
    for (int j = 0; j < 4; ++j) {
      int col = bn + tx * 4 + j;
      out[(size_t)row * DD + col] = acc[i2][j] + bias[col];
    }
  }
}

__global__ __launch_bounds__(256) void k_ln_rows(
    float* __restrict__ io, const float* __restrict__ mask,
    const float* __restrict__ g, const float* __restrict__ b) {
  const int r = blockIdx.x;
  float* row = io + (size_t)r * DD;
  const int tid = threadIdx.x;
  float x0 = row[tid], x1 = row[tid + 256];
  float s = x0 + x1, ss = x0 * x0 + x1 * x1;
#pragma unroll
  for (int off = 32; off > 0; off >>= 1) {
    s += __shfl_down(s, off, 64);
    ss += __shfl_down(ss, off, 64);
  }
  __shared__ float red[8];
  int lane = tid & 63, wv = tid >> 6;
  if (lane == 0) { red[wv] = s; red[4 + wv] = ss; }
  __syncthreads();
  s = red[0] + red[1] + red[2] + red[3];
  ss = red[4] + red[5] + red[6] + red[7];
  float mean = s * (1.0f / DD);
  float var = ss * (1.0f / DD) - mean * mean;
  float rs = rsqrtf(var + LN_EPS);
  float m = mask[r];
  row[tid] = ((x0 - mean) * rs * g[tid] + b[tid]) * m;
  row[tid + 256] = ((x1 - mean) * rs * g[tid + 256] + b[tid + 256]) * m;
}

// ---- transpose seq2 (n,t,k) -> xT[t][k][n] -------------------------------
__global__ __launch_bounds__(256) void k_xt(const float* __restrict__ seq2,
                                            float* __restrict__ xT) {
  __shared__ float tl[64][65];
  const int t = blockIdx.x;
  const int kt = blockIdx.y * 64;
  const int n = threadIdx.x >> 2;
  const int f = threadIdx.x & 3;
#pragma unroll
  for (int u = 0; u < 4; ++u) {
    int k = f * 16 + u * 4;
    float4 v = *(const float4*)(seq2 + ((size_t)n * SS + t) * DD + kt + k);
    tl[k + 0][n] = v.x;
    tl[k + 1][n] = v.y;
    tl[k + 2][n] = v.z;
    tl[k + 3][n] = v.w;
  }
  __syncthreads();
  const int k2 = threadIdx.x >> 2;
#pragma unroll
  for (int u = 0; u < 4; ++u) {
    int nn = f * 16 + u * 4;
    float4 v = make_float4(tl[k2][nn], tl[k2][nn + 1], tl[k2][nn + 2],
                           tl[k2][nn + 3]);
    *(float4*)(xT + ((size_t)t * DD + kt + k2) * 64 + nn) = v;
  }
}

// ---- pack W1 per block: W1p[b][k][c] = (k<512? g[k]:1) * W1[k][4b+c] ----
__global__ __launch_bounds__(256) void k_pack1(const float* __restrict__ W1,
                                               const float* __restrict__ ln_g,
                                               float* __restrict__ W1p) {
  int i = blockIdx.x * 256 + threadIdx.x;
  int bb = i >> 12;
  int k = (i >> 2) & 1023;
  int c = i & 3;
  float v = W1[(size_t)k * CC + bb * 4 + c];
  if (k < 512) v *= ln_g[k];
  W1p[i] = v;
}

// ---- pack W2 per block: W2p[g][k][q*2+j] = W2[k][q*512+2g+j] -------------
__global__ __launch_bounds__(256) void k_pack2(const float* __restrict__ W2,
                                               float* __restrict__ W2p) {
  int i = blockIdx.x * 256 + threadIdx.x;
  int g = i >> 13;
  int k = (i >> 3) & 1023;
  int q = (i >> 1) & 3;
  int j = i & 1;
  W2p[i] = W2[(size_t)k * FF + q * 512 + 2 * g + j];
}

// ---- column sums + zero sync words ---------------------------------------
__global__ __launch_bounds__(128) void k_cols(
    const float* __restrict__ W1, const float* __restrict__ b1,
    const float* __restrict__ ln_g, const float* __restrict__ ln_b,
    const float* __restrict__ START, float* __restrict__ Qc,
    float* __restrict__ Blnc, float* __restrict__ H0c,
    unsigned* __restrict__ sync) {
  int c = blockIdx.x * 128 + threadIdx.x;
  sync[c] = 0u;  // zeroes counters + epoch (first 3 used)
  float q = 0.f, bl = 0.f, h = 0.f;
  for (int k = 0; k < 512; ++k) {
    float wv = W1[(size_t)k * CC + c];
    q = fmaf(ln_g[k], wv, q);
    bl = fmaf(ln_b[k], wv, bl);
    h = fmaf(START[k], wv, h);
  }
  float bias = b1[c];
  Qc[c] = q;
  Blnc[c] = bl + bias;
  H0c[c] = h + bias;
}

// ---------------- persistent scan (plain launch, 256x512) -----------------
__global__ __launch_bounds__(512, 1) void scan_kernel(
    float* __restrict__ outseq, float* __restrict__ gsout,
    const float* __restrict__ mask, const float* __restrict__ START,
    const float* __restrict__ W1p, const float* __restrict__ W2p,
    const float* __restrict__ b2, const float* __restrict__ ln_g,
    const float* __restrict__ ln_b, const float* __restrict__ Qc,
    const float* __restrict__ Blnc, const float* __restrict__ H0c,
    float* __restrict__ interT, float* __restrict__ zT,
    float* __restrict__ st_sum, float* __restrict__ st_ss,
    const float* __restrict__ xT, unsigned* __restrict__ sync,
    const int use_xt) {
  const int b = blockIdx.x;
  const int tid = threadIdx.x;
  const int w = tid >> 6;
  const int lane = tid & 63;
  const int d0 = 2 * b;
  unsigned ep = 0;

  __shared__ float4 pA4[8][64];
  __shared__ float4 pB4[8][64][2];

  float ht0 = 0, ht1 = 0, gs0 = 0, gs1 = 0, z0 = 0, z1 = 0;
  float gg0 = 0, gg1 = 0, bb0 = 0, bb1 = 0, mn = 0, rv = 0;
  if (tid < 64) {
    ht0 = START[d0];
    ht1 = START[d0 + 1];
    gs0 = ht0;
    gs1 = ht1;
    gg0 = ln_g[d0];
    gg1 = ln_g[d0 + 1];
    bb0 = ln_b[d0];
    bb1 = ln_b[d0 + 1];
  }
  const float4 Q4 = *(const float4*)(Qc + 4 * b);
  const float4 Bl4 = *(const float4*)(Blnc + 4 * b);
  const float4 H04 = *(const float4*)(H0c + 4 * b);
  float bb2[8];
#pragma unroll
  for (int q = 0; q < 4; ++q) {
    bb2[2 * q] = b2[q * 512 + d0];
    bb2[2 * q + 1] = b2[q * 512 + d0 + 1];
  }

  for (int t = 0; t < SS; ++t) {
    // ---------- A-head: finalize step t-1 (owners), coherent stat reads ---
    if (t > 0 && tid < 64) {
      const int par = ((t - 1) & 1) << 11;
      const float* sp = st_sum + par + (tid << 5);
      const float* qp = st_ss + par + (tid << 5);
      float s = 0.f, ss = 0.f;
#pragma unroll
      for (int i = 0; i < 32; ++i) {
        s += cload(sp + i);
        ss += cload(qp + i);
      }
      float mean = s * (1.0f / DD);
      float var = ss * (1.0f / DD) - mean * mean;
      float rsv = rsqrtf(var + LN_EPS);
      mn = mean;
      rv = rsv;
      float hn0 = (z0 - mean) * rsv * gg0 + bb0;
      float hn1 = (z1 - mean) * rsv * gg1 + bb1;
      float m = mask[tid * SS + (t - 1)];
      *(float2*)(outseq + (size_t)tid * SS * DD + (size_t)(t - 1) * DD + d0) =
          make_float2(hn0 * m, hn1 * m);
      gs0 = m * hn0 + (1.0f - m) * gs0;
      gs1 = m * hn1 + (1.0f - m) * gs1;
      ht0 = hn0;
      ht1 = hn1;
    }
    if (b == 0) {  // zero parity t&1 (used by B(t) atomics after barrier 1)
      const int parz = (t & 1) << 11;
#pragma unroll
      for (int i = 0; i < 4; ++i) {
        cstore(st_sum + parz + tid + i * 512, 0.f);
        cstore(st_ss + parz + tid + i * 512, 0.f);
      }
    }
    // ---------- A waves: gemm1 partials (32-deep prefetch) ----------
    {
      const int k0 = w << 7;
      float4 acc = make_float4(0.f, 0.f, 0.f, 0.f);
      const float* wp = W1p + ((size_t)b << 12) + (k0 << 2);
      if (w < 4) {
        if (t > 0) {  // z-part: coherent loads (cross-block data)
          const float* ap = zT + k0 * 64 + lane;
          for (int c0 = 0; c0 < 128; c0 += 32) {
            float v[32];
#pragma unroll
            for (int j = 0; j < 32; ++j) v[j] = cload(ap + ((c0 + j) << 6));
#pragma unroll
            for (int j = 0; j < 32; ++j) {
              const float* wr = wp + ((c0 + j) << 2);
              acc.x = fmaf(v[j], wr[0], acc.x);
              acc.y = fmaf(v[j], wr[1], acc.y);
              acc.z = fmaf(v[j], wr[2], acc.z);
              acc.w = fmaf(v[j], wr[3], acc.w);
            }
          }
        }
      } else {
        const int kx = k0 - 512;
        if (use_xt) {  // x-part: read-only prologue data, cached loads
          const float* xp = xT + ((size_t)t * DD + kx) * 64 + lane;
          for (int c0 = 0; c0 < 128; c0 += 32) {
            float v[32];
#pragma unroll
            for (int j = 0; j < 32; ++j) v[j] = xp[(c0 + j) << 6];
#pragma unroll
            for (int j = 0; j < 32; ++j) {
              const float* wr = wp + ((c0 + j) << 2);
              acc.x = fmaf(v[j], wr[0], acc.x);
              acc.y = fmaf(v[j], wr[1], acc.y);
              acc.z = fmaf(v[j], wr[2], acc.z);
              acc.w = fmaf(v[j], wr[3], acc.w);
            }
          }
        } else {
          const float* op =
              outseq + (size_t)lane * SS * DD + (size_t)t * DD + kx;
          for (int c0 = 0; c0 < 128; c0 += 16) {
            float4 xv[4];
#pragma unroll
            for (int j = 0; j < 4; ++j)
              xv[j] = *(const float4*)(op + c0 + 4 * j);
#pragma unroll
            for (int j = 0; j < 16; ++j) {
              const float* wr = wp + ((c0 + j) << 2);
              float x = ((const float*)xv)[j];
              acc.x = fmaf(x, wr[0], acc.x);
              acc.y = fmaf(x, wr[1], acc.y);
              acc.z = fmaf(x, wr[2], acc.z);
              acc.w = fmaf(x, wr[3], acc.w);
            }
          }
        }
      }
      pA4[w][lane] = acc;
    }
    __syncthreads();
    // ---------- A-tail: epilogue (LN fold) + gelu -> interT (coherent) ----
    if (tid < 64) {
      float4 P = pA4[0][tid];
      float4 X = pA4[4][tid];
#pragma unroll
      for (int ww = 1; ww < 4; ++ww) {
        float4 p = pA4[ww][tid];
        P.x += p.x; P.y += p.y; P.z += p.z; P.w += p.w;
        float4 x4 = pA4[ww + 4][tid];
        X.x += x4.x; X.y += x4.y; X.z += x4.z; X.w += x4.w;
      }
      float4 o;
      if (t > 0) {
        float c1 = -rv * mn;
        o.x = fmaf(rv, P.x, fmaf(c1, Q4.x, Bl4.x)) + X.x;
        o.y = fmaf(rv, P.y, fmaf(c1, Q4.y, Bl4.y)) + X.y;
        o.z = fmaf(rv, P.z, fmaf(c1, Q4.z, Bl4.z)) + X.z;
        o.w = fmaf(rv, P.w, fmaf(c1, Q4.w, Bl4.w)) + X.w;
      } else {
        o.x = H04.x + X.x;
        o.y = H04.y + X.y;
        o.z = H04.z + X.z;
        o.w = H04.w + X.w;
      }
      cstore(interT + (4 * b + 0) * 64 + tid, geluf(o.x));
      cstore(interT + (4 * b + 1) * 64 + tid, geluf(o.y));
      cstore(interT + (4 * b + 2) * 64 + tid, geluf(o.z));
      cstore(interT + (4 * b + 3) * 64 + tid, geluf(o.w));
    }
    gbar(sync, ++ep);  // barrier 1: interT visible
    // ---------- B waves: gemm2 partials (coherent interT loads) ----------
    {
      const int k0 = w << 7;
      float4 accL = make_float4(0.f, 0.f, 0.f, 0.f);
      float4 accH = make_float4(0.f, 0.f, 0.f, 0.f);
      const float* w2 = W2p + ((size_t)b << 13) + (k0 << 3);
      const float* ip = interT + k0 * 64 + lane;
      for (int c0 = 0; c0 < 128; c0 += 32) {
        float v[32];
#pragma unroll
        for (int j = 0; j < 32; ++j) v[j] = cload(ip + ((c0 + j) << 6));
#pragma unroll
        for (int j = 0; j < 32; ++j) {
          const float* wr = w2 + ((c0 + j) << 3);
          accL.x = fmaf(v[j], wr[0], accL.x);
          accL.y = fmaf(v[j], wr[1], accL.y);
          accL.z = fmaf(v[j], wr[2], accL.z);
          accL.w = fmaf(v[j], wr[3], accL.w);
          accH.x = fmaf(v[j], wr[4], accH.x);
          accH.y = fmaf(v[j], wr[5], accH.y);
          accH.z = fmaf(v[j], wr[6], accH.z);
          accH.w = fmaf(v[j], wr[7], accH.w);
        }
      }
      pB4[w][lane][0] = accL;
      pB4[w][lane][1] = accH;
    }
    __syncthreads();
    // ---------- B-tail: gates -> z (coherent), stats atomics --------------
    if (tid < 64) {
      float4 lo = pB4[0][tid][0];
      float4 hi = pB4[0][tid][1];
#pragma unroll
      for (int ww = 1; ww < 8; ++ww) {
        float4 p = pB4[ww][tid][0];
        lo.x += p.x; lo.y += p.y; lo.z += p.z; lo.w += p.w;
        float4 q = pB4[ww][tid][1];
        hi.x += q.x; hi.y += q.y; hi.z += q.z; hi.w += q.w;
      }
      lo.x += bb2[0]; lo.y += bb2[1]; lo.z += bb2[2]; lo.w += bb2[3];
      hi.x += bb2[4]; hi.y += bb2[5]; hi.z += bb2[6]; hi.w += bb2[7];
      float x0, x1;
      if (use_xt) {
        x0 = xT[((size_t)t * DD + d0) * 64 + tid];
        x1 = xT[((size_t)t * DD + d0 + 1) * 64 + tid];
      } else {
        float2 x2 = *(const float2*)(outseq + (size_t)tid * SS * DD +
                                     (size_t)t * DD + d0);
        x0 = x2.x;
        x1 = x2.y;
      }
      z0 = sigf(lo.x) * ht0 + sigf(lo.z) * x0 + sigf(hi.x) * hi.z;
      z1 = sigf(lo.y) * ht1 + sigf(lo.w) * x1 + sigf(hi.y) * hi.w;
      cstore(zT + d0 * 64 + tid, z0);
      cstore(zT + (d0 + 1) * 64 + tid, z1);
      const int par = (t & 1) << 11;
      const int slot = b & 31;
      atomicAdd(st_sum + par + (tid << 5) + slot, z0 + z1);
      atomicAdd(st_ss + par + (tid << 5) + slot, z0 * z0 + z1 * z1);
    }
    gbar(sync, ++ep);  // barrier 2: z + stats visible
  }
  // ---------- flush step 511 ----------
  if (tid < 64) {
    const int par = ((SS - 1) & 1) << 11;
    const float* sp = st_sum + par + (tid << 5);
    const float* qp = st_ss + par + (tid << 5);
    float s = 0.f, ss = 0.f;
#pragma unroll
    for (int i = 0; i < 32; ++i) {
      s += cload(sp + i);
      ss += cload(qp + i);
    }
    float mean = s * (1.0f / DD);
    float var = ss * (1.0f / DD) - mean * mean;
    float rsv = rsqrtf(var + LN_EPS);
    float hn0 = (z0 - mean) * rsv * gg0 + bb0;
    float hn1 = (z1 - mean) * rsv * gg1 + bb1;
    float m = mask[tid * SS + (SS - 1)];
    *(float2*)(outseq + (size_t)tid * SS * DD + (size_t)(SS - 1) * DD + d0) =
        make_float2(hn0 * m, hn1 * m);
    gs0 = m * hn0 + (1.0f - m) * gs0;
    gs1 = m * hn1 + (1.0f - m) * gs1;
    *(float2*)(gsout + tid * DD + d0) = make_float2(gs0, gs1);
  }
}

// ---------------- host ----------------------------------------------------
extern "C" void kernel_launch(void* const* d_in, const int* in_sizes, int n_in,
                              void* d_out, int out_size, void* d_ws,
                              size_t ws_size, hipStream_t stream) {
  const float* seq = (const float*)d_in[0];
  const float* mask = (const float*)d_in[1];
  const float* START = (const float*)d_in[2];
  const float* W_init = (const float*)d_in[3];
  const float* b_init = (const float*)d_in[4];
  const float* W1 = (const float*)d_in[5];
  const float* b1 = (const float*)d_in[6];
  const float* W2 = (const float*)d_in[7];
  const float* b2 = (const float*)d_in[8];
  const float* ln_g = (const float*)d_in[9];
  const float* ln_b = (const float*)d_in[10];

  float* out = (float*)d_out;
  float* outseq = out;
  float* gsout = out + (size_t)NB * SS * DD;

  float* W1p = (float*)d_ws;              // 1,048,576
  float* W2p = W1p + 1048576;             // 2,097,152
  float* interT = W2p + 2097152;          // 65,536
  float* zT = interT + 65536;             // 32,768
  float* st_sum = zT + 32768;             // 4,096
  float* st_ss = st_sum + 4096;           // 4,096
  float* Qc = st_ss + 4096;               // 1,024
  float* Blnc = Qc + 1024;                // 1,024
  float* H0c = Blnc + 1024;               // 1,024
  unsigned* syncw = (unsigned*)(H0c + 1024);  // 1,024 u32
  float* xT = (float*)(syncw + 1024);     // 16,777,216 (optional)
  const size_t base_floats = 1048576 + 2097152 + 65536 + 32768 + 4096 + 4096 +
                             1024 + 1024 + 1024 + 1024;
  const int use_xt =
      (ws_size >= (base_floats + (size_t)16777216) * 4) ? 1 : 0;

  dim3 ga(DD / 64, (NB * SS) / 64);
  k_gemm_init<<<ga, 256, 0, stream>>>(seq, mask, W_init, b_init, outseq);
  k_ln_rows<<<NB * SS, 256, 0, stream>>>(outseq, mask, ln_g, ln_b);
  if (use_xt) {
    k_xt<<<dim3(SS, 8), 256, 0, stream>>>(outseq, xT);
  }
  k_pack1<<<4096, 256, 0, stream>>>(W1, ln_g, W1p);
  k_pack2<<<8192, 256, 0, stream>>>(W2, W2p);
  k_cols<<<8, 128, 0, stream>>>(W1, b1, ln_g, ln_b, START, Qc, Blnc, H0c,
                                syncw);

  scan_kernel<<<256, 512, 0, stream>>>(outseq, gsout, mask, START, W1p, W2p,
                                       b2, ln_g, ln_b, Qc, Blnc, H0c, interT,
                                       zT, st_sum, st_ss, xT, syncw, use_xt);
}